// Round 11
// baseline (271.536 us; speedup 1.0000x reference)
//
#include <hip/hip_runtime.h>
#include <stdint.h>

// CIN (xDeepFM): B=1024, F=39, D=64, UNITS=[128,128,128]
// Fused per-b kernel: L1 -> X1^T in LDS -> L2 -> X2 in LDS -> gram G=X0·X2^T.
// pooled3[b,o] = sum_k W3[o,k]*G[b,k] in a second kernel (W3 frag-packed).
// R10: wave mapping (o-tile 64 x d-half 32) -> each sb (x0*Xi B-frag) feeds
// 4 MFMAs instead of 2, halving the redundant v_pk_mul_f16 work.

#define F_N 39
#define D_N 64
#define O_N 128

typedef _Float16 f16;
typedef _Float16 f16x8 __attribute__((ext_vector_type(8)));
typedef _Float16 f16x4 __attribute__((ext_vector_type(4)));
typedef float f32x4 __attribute__((ext_vector_type(4)));

__device__ __forceinline__ unsigned short h2u(f16 h) {
  union { f16 h; unsigned short u; } v; v.h = h; return v.u;
}

// ---- prep: repack W1/W2/W3 into MFMA-fragment layout (one kernel) ----
// y slot (16B units): ((h*KS+kk)*8 + wv*2 + p)*64 + lane
//   element: W[wv*32+p*16+(lane&15)][h*Mv + kk*32+(lane>>4)*8+j], 0 if m>=Mv
__device__ __forceinline__ void repack_one(const float* __restrict__ w,
                                           f16* __restrict__ y, int idx,
                                           int KS, int Mv, int RS) {
  int j = idx & 7, lane = (idx >> 3) & 63, p = (idx >> 9) & 1, wv = (idx >> 10) & 3;
  int kkh = idx >> 12, kk = kkh % KS, h = kkh / KS;
  int o = wv * 32 + p * 16 + (lane & 15);
  int m = kk * 32 + (lane >> 4) * 8 + j;
  y[idx] = (m < Mv) ? (f16)w[(size_t)o * RS + h * Mv + m] : (f16)0.f;
}

__global__ __launch_bounds__(256) void prep_k(const float* __restrict__ W1,
                                              const float* __restrict__ W2,
                                              const float* __restrict__ W3,
                                              f16* __restrict__ W1f,
                                              f16* __restrict__ W2f,
                                              f16* __restrict__ W3f) {
  int blk = blockIdx.x, t = threadIdx.x;
  if (blk < 1248) {
    repack_one(W1, W1f, blk * 256 + t, 2, 39, 1521);
  } else if (blk < 3744) {
    repack_one(W2, W2f, (blk - 1248) * 256 + t, 4, 128, 4992);
  } else {
    repack_one(W3, W3f, (blk - 3744) * 256 + t, 156, 4992, 4992);  // h==0
  }
}

// One CIN layer, d-split mapping. Wave (ot,dh): o-tile = ot*64..+63,
// d-half = dh*32..+31. bbr: 2 B-frags (d-half); A: 4 W-frags per kk.
// Internal barrier after bbr reads (caller may then overwrite xi_t).
template <int KS>
__device__ __forceinline__ void layer_mm(const f16* __restrict__ Wf_base,
                                         const unsigned short* xi_t,
                                         const f16* x0s,
                                         f32x4 (&accO)[4][2],
                                         int ot, int dh, int lane, int lr, int lg) {
  constexpr int MP = KS * 32;
  f16x8 bbr[KS][2];
  #pragma unroll
  for (int kk = 0; kk < KS; ++kk)
    #pragma unroll
    for (int nf = 0; nf < 2; ++nf) {
      const int n = (dh * 2 + nf) * 16 + lr;          // d index
      const int off = (n * (MP * 2) + (kk * 32 + lg * 8) * 2) ^ ((n & 7) << 4);
      bbr[kk][nf] = *(const f16x8*)((const char*)xi_t + off);
    }
  __syncthreads();   // xi_t reads complete before caller overwrites it

  const f16x8* Wf = (const f16x8*)Wf_base;
  const int wbase = ot * 256 + lane;
  f16x8 wA[KS][4], wB[KS][4];

  auto loadW = [&](f16x8 (&buf)[KS][4], int hh) {
    const f16x8* pw = Wf + (size_t)hh * (KS * 512) + wbase;
    #pragma unroll
    for (int kk = 0; kk < KS; ++kk)
      #pragma unroll
      for (int p = 0; p < 4; ++p)
        buf[kk][p] = pw[kk * 512 + p * 64];
  };

  auto body = [&](f16x8 (&buf)[KS][4], int h) {
    f16 sv[2];
    #pragma unroll
    for (int nf = 0; nf < 2; ++nf) sv[nf] = x0s[h * 64 + dh * 32 + nf * 16 + lr];
    #pragma unroll
    for (int kk = 0; kk < KS; ++kk)
      #pragma unroll
      for (int nf = 0; nf < 2; ++nf) {
        f16x8 sb = bbr[kk][nf] * sv[nf];   // v_pk_mul_f16: B' = x0*Xi
        #pragma unroll
        for (int p = 0; p < 4; ++p)
          accO[p][nf] = __builtin_amdgcn_mfma_f32_16x16x32_f16(buf[kk][p], sb, accO[p][nf], 0, 0, 0);
      }
  };

  loadW(wA, 0);
  for (int h = 0; h < F_N; h += 2) {
    loadW(wB, (h + 1 < F_N) ? h + 1 : F_N - 1);
    body(wA, h);
    loadW(wA, (h + 2 < F_N) ? h + 2 : F_N - 1);
    if (h + 1 < F_N) body(wB, h + 1);
  }
}

__global__ __launch_bounds__(256, 2) void cin_fused_k(
    const float* __restrict__ X0f,    // [1024][39][64] f32
    const f16* __restrict__ W1f,      // frag-packed
    const f16* __restrict__ W2f,      // frag-packed
    const float* __restrict__ b1,
    const float* __restrict__ b2,
    f16* __restrict__ Gb,             // [1024][4992] f16
    float* __restrict__ out)          // [1024][384] f32
{
  __shared__ __align__(16) unsigned short xi_t[8192];  // X0^T then X1^T, swizzled
  __shared__ __align__(16) unsigned short xbuf[8192];  // X2 [128][64] f16-bits
  __shared__ f16 x0s[48 * 64];                         // [h][d], rows 39..47 zero
  __shared__ float pld[2][128];                        // pooled partials per d-half

  const int b = blockIdx.x, t = threadIdx.x;
  const int wave = t >> 6, lane = t & 63, lr = lane & 15, lg = lane >> 4;
  const int ot = wave >> 1, dh = wave & 1;
  const f32x4 zero4 = {0.f, 0.f, 0.f, 0.f};
  const float* xs = X0f + (size_t)b * (F_N * D_N);

  // ---- phase A: stage X0^T (swizzled, m-padded to 64) + x0s f16 ----
  {
    const int d = t & 63, m0 = t >> 6;
    #pragma unroll
    for (int m = m0; m < 64; m += 4) {
      f16 v = (m < F_N) ? (f16)xs[m * 64 + d] : (f16)0.f;
      int off = (d * 128 + m * 2) ^ ((d & 7) << 4);
      *(unsigned short*)((char*)xi_t + off) = h2u(v);
    }
    for (int i = t; i < 3072; i += 256)
      x0s[i] = (i < F_N * D_N) ? (f16)xs[i] : (f16)0.f;
  }
  __syncthreads();

  // ---- layer 1 ----
  f32x4 accO[4][2];
  #pragma unroll
  for (int p = 0; p < 4; ++p)
    #pragma unroll
    for (int nf = 0; nf < 2; ++nf) accO[p][nf] = zero4;
  layer_mm<2>(W1f, xi_t, x0s, accO, ot, dh, lane, lr, lg);

  // epilogue 1: X1^T -> xi_t (transposed+swizzled, MP=128); pooled partials
  {
    float bv[4][4];
    #pragma unroll
    for (int p = 0; p < 4; ++p)
      #pragma unroll
      for (int r = 0; r < 4; ++r) bv[p][r] = b1[ot * 64 + p * 16 + lg * 4 + r];

    #pragma unroll
    for (int p = 0; p < 4; ++p)
      #pragma unroll
      for (int nf = 0; nf < 2; ++nf)
        #pragma unroll
        for (int r = 0; r < 4; ++r) {
          int o = ot * 64 + p * 16 + lg * 4 + r;   // m-index of X1
          int d = dh * 32 + nf * 16 + lr;
          f16 val = (f16)(accO[p][nf][r] + bv[p][r]);
          int off = (d * 256 + o * 2) ^ ((d & 7) << 4);
          *(unsigned short*)((char*)xi_t + off) = h2u(val);
        }

    #pragma unroll
    for (int p = 0; p < 4; ++p)
      #pragma unroll
      for (int r = 0; r < 4; ++r) {
        float v = accO[p][0][r] + accO[p][1][r];
        v += __shfl_xor(v, 1, 16);
        v += __shfl_xor(v, 2, 16);
        v += __shfl_xor(v, 4, 16);
        v += __shfl_xor(v, 8, 16);
        if (lr == 0) pld[dh][ot * 64 + p * 16 + lg * 4 + r] = v;
      }
  }
  __syncthreads();   // X1^T + pld visible
  if (t < 128) out[(size_t)b * 384 + t] = pld[0][t] + pld[1][t] + 64.0f * b1[t];

  // ---- layer 2 ----
  #pragma unroll
  for (int p = 0; p < 4; ++p)
    #pragma unroll
    for (int nf = 0; nf < 2; ++nf) accO[p][nf] = zero4;
  layer_mm<4>(W2f, xi_t, x0s, accO, ot, dh, lane, lr, lg);
  // (layer_mm's internal barrier also orders the pld[ ] pooled-1 reads above
  //  before the pld writes below)

  // epilogue 2: X2 -> xbuf [o][d]; pooled partials
  {
    float bv[4][4];
    #pragma unroll
    for (int p = 0; p < 4; ++p)
      #pragma unroll
      for (int r = 0; r < 4; ++r) bv[p][r] = b2[ot * 64 + p * 16 + lg * 4 + r];

    #pragma unroll
    for (int p = 0; p < 4; ++p)
      #pragma unroll
      for (int nf = 0; nf < 2; ++nf)
        #pragma unroll
        for (int r = 0; r < 4; ++r) {
          int o = ot * 64 + p * 16 + lg * 4 + r;
          int d = dh * 32 + nf * 16 + lr;
          xbuf[o * 64 + d] = h2u((f16)(accO[p][nf][r] + bv[p][r]));
        }

    #pragma unroll
    for (int p = 0; p < 4; ++p)
      #pragma unroll
      for (int r = 0; r < 4; ++r) {
        float v = accO[p][0][r] + accO[p][1][r];
        v += __shfl_xor(v, 1, 16);
        v += __shfl_xor(v, 2, 16);
        v += __shfl_xor(v, 4, 16);
        v += __shfl_xor(v, 8, 16);
        if (lr == 0) pld[dh][ot * 64 + p * 16 + lg * 4 + r] = v;
      }
  }
  __syncthreads();   // X2 + pld visible
  if (t < 128) out[(size_t)b * 384 + 128 + t] = pld[0][t] + pld[1][t] + 64.0f * b2[t];

  // ---- gram: G[h,m] = sum_d X0[h,d]*X2[m,d] (wave = m-tile of 32) ----
  {
    const f16* x2 = (const f16*)xbuf;
    f16x8 af[3][2], bfr[2][2];
    #pragma unroll
    for (int hf = 0; hf < 3; ++hf)     // A row = h (rows 39..47 zeros)
      #pragma unroll
      for (int kk = 0; kk < 2; ++kk)
        af[hf][kk] = *(const f16x8*)(x0s + (hf * 16 + lr) * 64 + kk * 32 + lg * 8);
    #pragma unroll
    for (int mf = 0; mf < 2; ++mf)     // B col = m
      #pragma unroll
      for (int kk = 0; kk < 2; ++kk)
        bfr[mf][kk] = *(const f16x8*)(x2 + (wave * 32 + mf * 16 + lr) * 64 + kk * 32 + lg * 8);

    f32x4 acc[3][2];
    #pragma unroll
    for (int hf = 0; hf < 3; ++hf)
      #pragma unroll
      for (int mf = 0; mf < 2; ++mf) {
        acc[hf][mf] = __builtin_amdgcn_mfma_f32_16x16x32_f16(af[hf][0], bfr[mf][0], zero4, 0, 0, 0);
        acc[hf][mf] = __builtin_amdgcn_mfma_f32_16x16x32_f16(af[hf][1], bfr[mf][1], acc[hf][mf], 0, 0, 0);
      }

    #pragma unroll
    for (int hf = 0; hf < 3; ++hf)
      #pragma unroll
      for (int mf = 0; mf < 2; ++mf)
        #pragma unroll
        for (int r = 0; r < 4; ++r) {
          int h = hf * 16 + lg * 4 + r;
          if (h < F_N)
            Gb[(size_t)b * 4992 + h * 128 + wave * 32 + mf * 16 + lr] = (f16)acc[hf][mf][r];
        }
  }
}

// pooled3[b,o] = sum_k W3[o,k]*G[b,k] + 64*b3[o]; K=4992=156*32
// W3f frag-packed: slot = ks*512 + wave*128 + q*64 + lane (coalesced loads)
__global__ __launch_bounds__(256) void pooled3_k(
    const f16* __restrict__ Gb,    // [1024][4992] f16
    const f16* __restrict__ W3f,   // frag-packed
    const float* __restrict__ b3,  // [128] f32
    float* __restrict__ out)       // [1024][384] f32
{
  const int b0 = blockIdx.x * 16, t = threadIdx.x;
  const int wave = t >> 6, lane = t & 63, lr = lane & 15, lg = lane >> 4;
  const f32x4 zero4 = {0.f, 0.f, 0.f, 0.f};

  const f16* ga = Gb + (size_t)(b0 + lr) * 4992 + lg * 8;   // A row = b
  const f16x8* wf = (const f16x8*)W3f;
  const int wbase = wave * 128 + lane;

  f32x4 acc0 = zero4, acc1 = zero4;
  #pragma unroll 4
  for (int ks = 0; ks < 156; ++ks) {
    f16x8 a  = *(const f16x8*)(ga + ks * 32);
    f16x8 q0 = wf[ks * 512 + wbase];
    f16x8 q1 = wf[ks * 512 + wbase + 64];
    acc0 = __builtin_amdgcn_mfma_f32_16x16x32_f16(a, q0, acc0, 0, 0, 0);
    acc1 = __builtin_amdgcn_mfma_f32_16x16x32_f16(a, q1, acc1, 0, 0, 0);
  }

  #pragma unroll
  for (int r = 0; r < 4; ++r) {
    int bb = b0 + lg * 4 + r;
    int o0 = wave * 32 + lr;
    out[(size_t)bb * 384 + 256 + o0]      = acc0[r] + 64.0f * b3[o0];
    out[(size_t)bb * 384 + 256 + o0 + 16] = acc1[r] + 64.0f * b3[o0 + 16];
  }
}

extern "C" void kernel_launch(void* const* d_in, const int* in_sizes, int n_in,
                              void* d_out, int out_size, void* d_ws, size_t ws_size,
                              hipStream_t stream) {
  const float* X0 = (const float*)d_in[0];
  const float* W1 = (const float*)d_in[1];
  const float* b1 = (const float*)d_in[2];
  const float* W2 = (const float*)d_in[3];
  const float* b2 = (const float*)d_in[4];
  const float* W3 = (const float*)d_in[5];
  const float* b3 = (const float*)d_in[6];
  float* out = (float*)d_out;

  // ws layout (f16 elements), ~13.4 MB total
  f16* W1f = (f16*)d_ws;            // 39*2*4096    = 319488
  f16* W2f = W1f + 319488;          // 39*4*4096    = 638976
  f16* W3f = W2f + 638976;          // 156*4096     = 638976
  f16* Gb  = W3f + 638976;          // 1024*4992    = 5111808

  prep_k<<<6240, 256, 0, stream>>>(W1, W2, W3, W1f, W2f, W3f);
  cin_fused_k<<<1024, 256, 0, stream>>>(X0, W1f, W2f, b1, b2, Gb, out);
  pooled3_k<<<64, 256, 0, stream>>>(Gb, W3f, b3, out);
}

// Round 12
// 253.870 us; speedup vs baseline: 1.0696x; 1.0696x over previous
//
#include <hip/hip_runtime.h>
#include <stdint.h>

// CIN (xDeepFM): B=1024, F=39, D=64, UNITS=[128,128,128]
// Fused per-b kernel: L1 -> X1^T in LDS -> L2 -> X2 in LDS -> gram G=X0·X2^T.
// pooled3[b,o] = sum_k W3[o,k]*G[b,k] in a second kernel (W3 frag-packed).
// R12: revert R10 d-split (W frags read ONCE per block; R11 showed the d-split
// doubled W L2 traffic to the 34.5 TB/s ceiling). Single 16KB LDS buffer for
// X0^T/X1^T/X2 (xbuf aliased onto xi_t) -> LDS 39.9->23.9 KB -> 4 blocks/CU.

#define F_N 39
#define D_N 64
#define O_N 128

typedef _Float16 f16;
typedef _Float16 f16x8 __attribute__((ext_vector_type(8)));
typedef _Float16 f16x4 __attribute__((ext_vector_type(4)));
typedef float f32x4 __attribute__((ext_vector_type(4)));

__device__ __forceinline__ unsigned short h2u(f16 h) {
  union { f16 h; unsigned short u; } v; v.h = h; return v.u;
}

// ---- prep: repack W1/W2/W3 into MFMA-fragment layout (one kernel) ----
// y slot (16B units): ((h*KS+kk)*8 + wv*2 + p)*64 + lane
//   element: W[wv*32+p*16+(lane&15)][h*Mv + kk*32+(lane>>4)*8+j], 0 if m>=Mv
__device__ __forceinline__ void repack_one(const float* __restrict__ w,
                                           f16* __restrict__ y, int idx,
                                           int KS, int Mv, int RS) {
  int j = idx & 7, lane = (idx >> 3) & 63, p = (idx >> 9) & 1, wv = (idx >> 10) & 3;
  int kkh = idx >> 12, kk = kkh % KS, h = kkh / KS;
  int o = wv * 32 + p * 16 + (lane & 15);
  int m = kk * 32 + (lane >> 4) * 8 + j;
  y[idx] = (m < Mv) ? (f16)w[(size_t)o * RS + h * Mv + m] : (f16)0.f;
}

__global__ __launch_bounds__(256) void prep_k(const float* __restrict__ W1,
                                              const float* __restrict__ W2,
                                              const float* __restrict__ W3,
                                              f16* __restrict__ W1f,
                                              f16* __restrict__ W2f,
                                              f16* __restrict__ W3f) {
  int blk = blockIdx.x, t = threadIdx.x;
  if (blk < 1248) {
    repack_one(W1, W1f, blk * 256 + t, 2, 39, 1521);
  } else if (blk < 3744) {
    repack_one(W2, W2f, (blk - 1248) * 256 + t, 4, 128, 4992);
  } else {
    repack_one(W3, W3f, (blk - 3744) * 256 + t, 156, 4992, 4992);  // h==0
  }
}

// One CIN layer, R9 mapping: wave = o-tile of 32 (2 frags), full d (4 nf).
// W frags read once per block. Internal barrier after bbr reads.
template <int KS>
__device__ __forceinline__ void layer_mm(const f16* __restrict__ Wf_base,
                                         const unsigned short* xi_t,
                                         const f16* x0s,
                                         f32x4 (&accO)[2][4],
                                         int wave, int lane, int lr, int lg) {
  constexpr int MP = KS * 32;
  f16x8 bbr[KS][4];
  #pragma unroll
  for (int kk = 0; kk < KS; ++kk)
    #pragma unroll
    for (int nf = 0; nf < 4; ++nf) {
      const int n = nf * 16 + lr;          // d index
      const int off = (n * (MP * 2) + (kk * 32 + lg * 8) * 2) ^ ((n & 7) << 4);
      bbr[kk][nf] = *(const f16x8*)((const char*)xi_t + off);
    }
  __syncthreads();   // xi_t reads complete before caller overwrites it

  const f16x8* Wf = (const f16x8*)Wf_base;
  const int wbase = wave * 128 + lane;
  f16x8 wA[KS][2], wB[KS][2];

  auto loadW = [&](f16x8 (&buf)[KS][2], int hh) {
    const f16x8* pw = Wf + (size_t)hh * (KS * 512) + wbase;
    #pragma unroll
    for (int kk = 0; kk < KS; ++kk)
      #pragma unroll
      for (int p = 0; p < 2; ++p)
        buf[kk][p] = pw[kk * 512 + p * 64];
  };

  auto body = [&](f16x8 (&buf)[KS][2], int h) {
    f16 sv[4];
    #pragma unroll
    for (int nf = 0; nf < 4; ++nf) sv[nf] = x0s[h * 64 + nf * 16 + lr];
    #pragma unroll
    for (int kk = 0; kk < KS; ++kk)
      #pragma unroll
      for (int nf = 0; nf < 4; ++nf) {
        f16x8 sb = bbr[kk][nf] * sv[nf];   // v_pk_mul_f16: B' = x0*Xi
        accO[0][nf] = __builtin_amdgcn_mfma_f32_16x16x32_f16(buf[kk][0], sb, accO[0][nf], 0, 0, 0);
        accO[1][nf] = __builtin_amdgcn_mfma_f32_16x16x32_f16(buf[kk][1], sb, accO[1][nf], 0, 0, 0);
      }
  };

  loadW(wA, 0);
  for (int h = 0; h < F_N; h += 2) {
    loadW(wB, (h + 1 < F_N) ? h + 1 : F_N - 1);
    body(wA, h);
    loadW(wA, (h + 2 < F_N) ? h + 2 : F_N - 1);
    if (h + 1 < F_N) body(wB, h + 1);
  }
}

__global__ __launch_bounds__(256, 2) void cin_fused_k(
    const float* __restrict__ X0f,    // [1024][39][64] f32
    const f16* __restrict__ W1f,      // frag-packed
    const f16* __restrict__ W2f,      // frag-packed
    const float* __restrict__ b1,
    const float* __restrict__ b2,
    f16* __restrict__ Gb,             // [1024][4992] f16
    float* __restrict__ out)          // [1024][384] f32
{
  // ONE 16KB buffer, time-shared: X0^T (swz) -> X1^T (swz) -> X2 [128][64] linear
  __shared__ __align__(16) unsigned short xi_t[8192];
  __shared__ f16 x0s[48 * 64];                         // [h][d], rows 39..47 zero
  __shared__ float pld[2][128];                        // pooled partials

  const int b = blockIdx.x, t = threadIdx.x;
  const int wave = t >> 6, lane = t & 63, lr = lane & 15, lg = lane >> 4;
  const f32x4 zero4 = {0.f, 0.f, 0.f, 0.f};
  const float* xs = X0f + (size_t)b * (F_N * D_N);

  // ---- phase A: stage X0^T (swizzled, m-padded to 64) + x0s f16 ----
  {
    const int d = t & 63, m0 = t >> 6;
    #pragma unroll
    for (int m = m0; m < 64; m += 4) {
      f16 v = (m < F_N) ? (f16)xs[m * 64 + d] : (f16)0.f;
      int off = (d * 128 + m * 2) ^ ((d & 7) << 4);
      *(unsigned short*)((char*)xi_t + off) = h2u(v);
    }
    for (int i = t; i < 3072; i += 256)
      x0s[i] = (i < F_N * D_N) ? (f16)xs[i] : (f16)0.f;
  }
  __syncthreads();

  // ---- layer 1 ----
  f32x4 accO[2][4];
  #pragma unroll
  for (int p = 0; p < 2; ++p)
    #pragma unroll
    for (int nf = 0; nf < 4; ++nf) accO[p][nf] = zero4;
  layer_mm<2>(W1f, xi_t, x0s, accO, wave, lane, lr, lg);

  // epilogue 1: X1^T -> xi_t (transposed+swizzled, MP=128); pooled partials
  {
    float bv[2][4];
    #pragma unroll
    for (int p = 0; p < 2; ++p)
      #pragma unroll
      for (int r = 0; r < 4; ++r) bv[p][r] = b1[wave * 32 + p * 16 + lg * 4 + r];

    #pragma unroll
    for (int p = 0; p < 2; ++p)
      #pragma unroll
      for (int nf = 0; nf < 4; ++nf)
        #pragma unroll
        for (int r = 0; r < 4; ++r) {
          int o = wave * 32 + p * 16 + lg * 4 + r;   // m-index of X1
          int d = nf * 16 + lr;
          f16 val = (f16)(accO[p][nf][r] + bv[p][r]);
          int off = (d * 256 + o * 2) ^ ((d & 7) << 4);
          *(unsigned short*)((char*)xi_t + off) = h2u(val);
        }

    #pragma unroll
    for (int p = 0; p < 2; ++p)
      #pragma unroll
      for (int r = 0; r < 4; ++r) {
        float v = accO[p][0][r] + accO[p][1][r] + accO[p][2][r] + accO[p][3][r];
        v += __shfl_xor(v, 1, 16);
        v += __shfl_xor(v, 2, 16);
        v += __shfl_xor(v, 4, 16);
        v += __shfl_xor(v, 8, 16);
        if (lr == 0) pld[0][wave * 32 + p * 16 + lg * 4 + r] = v;
      }
  }
  __syncthreads();   // X1^T + pld visible
  if (t < 128) out[(size_t)b * 384 + t] = pld[0][t] + 64.0f * b1[t];

  // ---- layer 2 ----
  #pragma unroll
  for (int p = 0; p < 2; ++p)
    #pragma unroll
    for (int nf = 0; nf < 4; ++nf) accO[p][nf] = zero4;
  layer_mm<4>(W2f, xi_t, x0s, accO, wave, lane, lr, lg);
  // layer_mm's internal barrier orders: (a) all X1^T bbr reads, and (b) the
  // pooled-1 out-writes' pld reads, BEFORE the xi_t/pld overwrites below.

  // epilogue 2: X2 -> xi_t as [m=128][d=64] linear f16; pooled partials
  {
    float bv[2][4];
    #pragma unroll
    for (int p = 0; p < 2; ++p)
      #pragma unroll
      for (int r = 0; r < 4; ++r) bv[p][r] = b2[wave * 32 + p * 16 + lg * 4 + r];

    #pragma unroll
    for (int p = 0; p < 2; ++p)
      #pragma unroll
      for (int nf = 0; nf < 4; ++nf)
        #pragma unroll
        for (int r = 0; r < 4; ++r) {
          int o = wave * 32 + p * 16 + lg * 4 + r;
          int d = nf * 16 + lr;
          xi_t[o * 64 + d] = h2u((f16)(accO[p][nf][r] + bv[p][r]));
        }

    #pragma unroll
    for (int p = 0; p < 2; ++p)
      #pragma unroll
      for (int r = 0; r < 4; ++r) {
        float v = accO[p][0][r] + accO[p][1][r] + accO[p][2][r] + accO[p][3][r];
        v += __shfl_xor(v, 1, 16);
        v += __shfl_xor(v, 2, 16);
        v += __shfl_xor(v, 4, 16);
        v += __shfl_xor(v, 8, 16);
        if (lr == 0) pld[1][wave * 32 + p * 16 + lg * 4 + r] = v;
      }
  }
  __syncthreads();   // X2 + pld visible
  if (t < 128) out[(size_t)b * 384 + 128 + t] = pld[1][t] + 64.0f * b2[t];

  // ---- gram: G[h,m] = sum_d X0[h,d]*X2[m,d] (wave = m-tile of 32) ----
  {
    const f16* x2 = (const f16*)xi_t;
    f16x8 af[3][2], bfr[2][2];
    #pragma unroll
    for (int hf = 0; hf < 3; ++hf)     // A row = h (rows 39..47 zeros)
      #pragma unroll
      for (int kk = 0; kk < 2; ++kk)
        af[hf][kk] = *(const f16x8*)(x0s + (hf * 16 + lr) * 64 + kk * 32 + lg * 8);
    #pragma unroll
    for (int mf = 0; mf < 2; ++mf)     // B col = m
      #pragma unroll
      for (int kk = 0; kk < 2; ++kk)
        bfr[mf][kk] = *(const f16x8*)(x2 + (wave * 32 + mf * 16 + lr) * 64 + kk * 32 + lg * 8);

    f32x4 acc[3][2];
    #pragma unroll
    for (int hf = 0; hf < 3; ++hf)
      #pragma unroll
      for (int mf = 0; mf < 2; ++mf) {
        acc[hf][mf] = __builtin_amdgcn_mfma_f32_16x16x32_f16(af[hf][0], bfr[mf][0], zero4, 0, 0, 0);
        acc[hf][mf] = __builtin_amdgcn_mfma_f32_16x16x32_f16(af[hf][1], bfr[mf][1], acc[hf][mf], 0, 0, 0);
      }

    #pragma unroll
    for (int hf = 0; hf < 3; ++hf)
      #pragma unroll
      for (int mf = 0; mf < 2; ++mf)
        #pragma unroll
        for (int r = 0; r < 4; ++r) {
          int h = hf * 16 + lg * 4 + r;
          if (h < F_N)
            Gb[(size_t)b * 4992 + h * 128 + wave * 32 + mf * 16 + lr] = (f16)acc[hf][mf][r];
        }
  }
}

// pooled3[b,o] = sum_k W3[o,k]*G[b,k] + 64*b3[o]; K=4992=156*32
// W3f frag-packed: slot = ks*512 + wave*128 + q*64 + lane (coalesced loads)
__global__ __launch_bounds__(256) void pooled3_k(
    const f16* __restrict__ Gb,    // [1024][4992] f16
    const f16* __restrict__ W3f,   // frag-packed
    const float* __restrict__ b3,  // [128] f32
    float* __restrict__ out)       // [1024][384] f32
{
  const int b0 = blockIdx.x * 16, t = threadIdx.x;
  const int wave = t >> 6, lane = t & 63, lr = lane & 15, lg = lane >> 4;
  const f32x4 zero4 = {0.f, 0.f, 0.f, 0.f};

  const f16* ga = Gb + (size_t)(b0 + lr) * 4992 + lg * 8;   // A row = b
  const f16x8* wf = (const f16x8*)W3f;
  const int wbase = wave * 128 + lane;

  f32x4 acc0 = zero4, acc1 = zero4;
  #pragma unroll 4
  for (int ks = 0; ks < 156; ++ks) {
    f16x8 a  = *(const f16x8*)(ga + ks * 32);
    f16x8 q0 = wf[ks * 512 + wbase];
    f16x8 q1 = wf[ks * 512 + wbase + 64];
    acc0 = __builtin_amdgcn_mfma_f32_16x16x32_f16(a, q0, acc0, 0, 0, 0);
    acc1 = __builtin_amdgcn_mfma_f32_16x16x32_f16(a, q1, acc1, 0, 0, 0);
  }

  #pragma unroll
  for (int r = 0; r < 4; ++r) {
    int bb = b0 + lg * 4 + r;
    int o0 = wave * 32 + lr;
    out[(size_t)bb * 384 + 256 + o0]      = acc0[r] + 64.0f * b3[o0];
    out[(size_t)bb * 384 + 256 + o0 + 16] = acc1[r] + 64.0f * b3[o0 + 16];
  }
}

extern "C" void kernel_launch(void* const* d_in, const int* in_sizes, int n_in,
                              void* d_out, int out_size, void* d_ws, size_t ws_size,
                              hipStream_t stream) {
  const float* X0 = (const float*)d_in[0];
  const float* W1 = (const float*)d_in[1];
  const float* b1 = (const float*)d_in[2];
  const float* W2 = (const float*)d_in[3];
  const float* b2 = (const float*)d_in[4];
  const float* W3 = (const float*)d_in[5];
  const float* b3 = (const float*)d_in[6];
  float* out = (float*)d_out;

  // ws layout (f16 elements), ~13.4 MB total
  f16* W1f = (f16*)d_ws;            // 39*2*4096    = 319488
  f16* W2f = W1f + 319488;          // 39*4*4096    = 638976
  f16* W3f = W2f + 638976;          // 156*4096     = 638976
  f16* Gb  = W3f + 638976;          // 1024*4992    = 5111808

  prep_k<<<6240, 256, 0, stream>>>(W1, W2, W3, W1f, W2f, W3f);
  cin_fused_k<<<1024, 256, 0, stream>>>(X0, W1f, W2f, b1, b2, Gb, out);
  pooled3_k<<<64, 256, 0, stream>>>(Gb, W3f, b3, out);
}

// Round 15
// 218.793 us; speedup vs baseline: 1.2411x; 1.1603x over previous
//
#include <hip/hip_runtime.h>
#include <stdint.h>

// CIN (xDeepFM): B=1024, F=39, D=64, UNITS=[128,128,128]
// Fused per-b kernel: L1 -> X1^T in LDS -> L2 -> X2 in LDS -> gram G=X0·X2^T.
// pooled3[b,o] = sum_k W3[o,k]*G[b,k].
// R13: pooled3 re-shaped 64 -> 512 blocks (64 b-grp x 8 o-grp, 4-way K-split
// across waves + LDS reduce). R12's 64-block version was HBM-latency-bound
// (~80us hidden cost: 6% occupancy, gather loads).

#define F_N 39
#define D_N 64
#define O_N 128

typedef _Float16 f16;
typedef _Float16 f16x8 __attribute__((ext_vector_type(8)));
typedef _Float16 f16x4 __attribute__((ext_vector_type(4)));
typedef float f32x4 __attribute__((ext_vector_type(4)));

__device__ __forceinline__ unsigned short h2u(f16 h) {
  union { f16 h; unsigned short u; } v; v.h = h; return v.u;
}

// ---- prep: repack W1/W2/W3 into MFMA-fragment layout (one kernel) ----
// y slot (16B units): ((h*KS+kk)*8 + wv*2 + p)*64 + lane
//   element: W[wv*32+p*16+(lane&15)][h*Mv + kk*32+(lane>>4)*8+j], 0 if m>=Mv
__device__ __forceinline__ void repack_one(const float* __restrict__ w,
                                           f16* __restrict__ y, int idx,
                                           int KS, int Mv, int RS) {
  int j = idx & 7, lane = (idx >> 3) & 63, p = (idx >> 9) & 1, wv = (idx >> 10) & 3;
  int kkh = idx >> 12, kk = kkh % KS, h = kkh / KS;
  int o = wv * 32 + p * 16 + (lane & 15);
  int m = kk * 32 + (lane >> 4) * 8 + j;
  y[idx] = (m < Mv) ? (f16)w[(size_t)o * RS + h * Mv + m] : (f16)0.f;
}

__global__ __launch_bounds__(256) void prep_k(const float* __restrict__ W1,
                                              const float* __restrict__ W2,
                                              const float* __restrict__ W3,
                                              f16* __restrict__ W1f,
                                              f16* __restrict__ W2f,
                                              f16* __restrict__ W3f) {
  int blk = blockIdx.x, t = threadIdx.x;
  if (blk < 1248) {
    repack_one(W1, W1f, blk * 256 + t, 2, 39, 1521);
  } else if (blk < 3744) {
    repack_one(W2, W2f, (blk - 1248) * 256 + t, 4, 128, 4992);
  } else {
    repack_one(W3, W3f, (blk - 3744) * 256 + t, 156, 4992, 4992);  // h==0
  }
}

// One CIN layer, wave = o-tile of 32 (2 frags), full d (4 nf).
// W frags read once per block. Internal barrier after bbr reads.
template <int KS>
__device__ __forceinline__ void layer_mm(const f16* __restrict__ Wf_base,
                                         const unsigned short* xi_t,
                                         const f16* x0s,
                                         f32x4 (&accO)[2][4],
                                         int wave, int lane, int lr, int lg) {
  constexpr int MP = KS * 32;
  f16x8 bbr[KS][4];
  #pragma unroll
  for (int kk = 0; kk < KS; ++kk)
    #pragma unroll
    for (int nf = 0; nf < 4; ++nf) {
      const int n = nf * 16 + lr;          // d index
      const int off = (n * (MP * 2) + (kk * 32 + lg * 8) * 2) ^ ((n & 7) << 4);
      bbr[kk][nf] = *(const f16x8*)((const char*)xi_t + off);
    }
  __syncthreads();   // xi_t reads complete before caller overwrites it

  const f16x8* Wf = (const f16x8*)Wf_base;
  const int wbase = wave * 128 + lane;
  f16x8 wA[KS][2], wB[KS][2];

  auto loadW = [&](f16x8 (&buf)[KS][2], int hh) {
    const f16x8* pw = Wf + (size_t)hh * (KS * 512) + wbase;
    #pragma unroll
    for (int kk = 0; kk < KS; ++kk)
      #pragma unroll
      for (int p = 0; p < 2; ++p)
        buf[kk][p] = pw[kk * 512 + p * 64];
  };

  auto body = [&](f16x8 (&buf)[KS][2], int h) {
    f16 sv[4];
    #pragma unroll
    for (int nf = 0; nf < 4; ++nf) sv[nf] = x0s[h * 64 + nf * 16 + lr];
    #pragma unroll
    for (int kk = 0; kk < KS; ++kk)
      #pragma unroll
      for (int nf = 0; nf < 4; ++nf) {
        f16x8 sb = bbr[kk][nf] * sv[nf];   // v_pk_mul_f16: B' = x0*Xi
        accO[0][nf] = __builtin_amdgcn_mfma_f32_16x16x32_f16(buf[kk][0], sb, accO[0][nf], 0, 0, 0);
        accO[1][nf] = __builtin_amdgcn_mfma_f32_16x16x32_f16(buf[kk][1], sb, accO[1][nf], 0, 0, 0);
      }
  };

  loadW(wA, 0);
  for (int h = 0; h < F_N; h += 2) {
    loadW(wB, (h + 1 < F_N) ? h + 1 : F_N - 1);
    body(wA, h);
    loadW(wA, (h + 2 < F_N) ? h + 2 : F_N - 1);
    if (h + 1 < F_N) body(wB, h + 1);
  }
}

__global__ __launch_bounds__(256, 2) void cin_fused_k(
    const float* __restrict__ X0f,    // [1024][39][64] f32
    const f16* __restrict__ W1f,      // frag-packed
    const f16* __restrict__ W2f,      // frag-packed
    const float* __restrict__ b1,
    const float* __restrict__ b2,
    f16* __restrict__ Gb,             // [1024][4992] f16
    float* __restrict__ out)          // [1024][384] f32
{
  // ONE 16KB buffer, time-shared: X0^T (swz) -> X1^T (swz) -> X2 [128][64] linear
  __shared__ __align__(16) unsigned short xi_t[8192];
  __shared__ f16 x0s[48 * 64];                         // [h][d], rows 39..47 zero
  __shared__ float pld[2][128];                        // pooled partials

  const int b = blockIdx.x, t = threadIdx.x;
  const int wave = t >> 6, lane = t & 63, lr = lane & 15, lg = lane >> 4;
  const f32x4 zero4 = {0.f, 0.f, 0.f, 0.f};
  const float* xs = X0f + (size_t)b * (F_N * D_N);

  // ---- phase A: stage X0^T (swizzled, m-padded to 64) + x0s f16 ----
  {
    const int d = t & 63, m0 = t >> 6;
    #pragma unroll
    for (int m = m0; m < 64; m += 4) {
      f16 v = (m < F_N) ? (f16)xs[m * 64 + d] : (f16)0.f;
      int off = (d * 128 + m * 2) ^ ((d & 7) << 4);
      *(unsigned short*)((char*)xi_t + off) = h2u(v);
    }
    for (int i = t; i < 3072; i += 256)
      x0s[i] = (i < F_N * D_N) ? (f16)xs[i] : (f16)0.f;
  }
  __syncthreads();

  // ---- layer 1 ----
  f32x4 accO[2][4];
  #pragma unroll
  for (int p = 0; p < 2; ++p)
    #pragma unroll
    for (int nf = 0; nf < 4; ++nf) accO[p][nf] = zero4;
  layer_mm<2>(W1f, xi_t, x0s, accO, wave, lane, lr, lg);

  // epilogue 1: X1^T -> xi_t (transposed+swizzled, MP=128); pooled partials
  {
    float bv[2][4];
    #pragma unroll
    for (int p = 0; p < 2; ++p)
      #pragma unroll
      for (int r = 0; r < 4; ++r) bv[p][r] = b1[wave * 32 + p * 16 + lg * 4 + r];

    #pragma unroll
    for (int p = 0; p < 2; ++p)
      #pragma unroll
      for (int nf = 0; nf < 4; ++nf)
        #pragma unroll
        for (int r = 0; r < 4; ++r) {
          int o = wave * 32 + p * 16 + lg * 4 + r;   // m-index of X1
          int d = nf * 16 + lr;
          f16 val = (f16)(accO[p][nf][r] + bv[p][r]);
          int off = (d * 256 + o * 2) ^ ((d & 7) << 4);
          *(unsigned short*)((char*)xi_t + off) = h2u(val);
        }

    #pragma unroll
    for (int p = 0; p < 2; ++p)
      #pragma unroll
      for (int r = 0; r < 4; ++r) {
        float v = accO[p][0][r] + accO[p][1][r] + accO[p][2][r] + accO[p][3][r];
        v += __shfl_xor(v, 1, 16);
        v += __shfl_xor(v, 2, 16);
        v += __shfl_xor(v, 4, 16);
        v += __shfl_xor(v, 8, 16);
        if (lr == 0) pld[0][wave * 32 + p * 16 + lg * 4 + r] = v;
      }
  }
  __syncthreads();   // X1^T + pld visible
  if (t < 128) out[(size_t)b * 384 + t] = pld[0][t] + 64.0f * b1[t];

  // ---- layer 2 ----
  #pragma unroll
  for (int p = 0; p < 2; ++p)
    #pragma unroll
    for (int nf = 0; nf < 4; ++nf) accO[p][nf] = zero4;
  layer_mm<4>(W2f, xi_t, x0s, accO, wave, lane, lr, lg);
  // layer_mm's internal barrier orders: (a) all X1^T bbr reads, and (b) the
  // pooled-1 out-writes' pld reads, BEFORE the xi_t/pld overwrites below.

  // epilogue 2: X2 -> xi_t as [m=128][d=64] linear f16; pooled partials
  {
    float bv[2][4];
    #pragma unroll
    for (int p = 0; p < 2; ++p)
      #pragma unroll
      for (int r = 0; r < 4; ++r) bv[p][r] = b2[wave * 32 + p * 16 + lg * 4 + r];

    #pragma unroll
    for (int p = 0; p < 2; ++p)
      #pragma unroll
      for (int nf = 0; nf < 4; ++nf)
        #pragma unroll
        for (int r = 0; r < 4; ++r) {
          int o = wave * 32 + p * 16 + lg * 4 + r;
          int d = nf * 16 + lr;
          xi_t[o * 64 + d] = h2u((f16)(accO[p][nf][r] + bv[p][r]));
        }

    #pragma unroll
    for (int p = 0; p < 2; ++p)
      #pragma unroll
      for (int r = 0; r < 4; ++r) {
        float v = accO[p][0][r] + accO[p][1][r] + accO[p][2][r] + accO[p][3][r];
        v += __shfl_xor(v, 1, 16);
        v += __shfl_xor(v, 2, 16);
        v += __shfl_xor(v, 4, 16);
        v += __shfl_xor(v, 8, 16);
        if (lr == 0) pld[1][wave * 32 + p * 16 + lg * 4 + r] = v;
      }
  }
  __syncthreads();   // X2 + pld visible
  if (t < 128) out[(size_t)b * 384 + 128 + t] = pld[1][t] + 64.0f * b2[t];

  // ---- gram: G[h,m] = sum_d X0[h,d]*X2[m,d] (wave = m-tile of 32) ----
  {
    const f16* x2 = (const f16*)xi_t;
    f16x8 af[3][2], bfr[2][2];
    #pragma unroll
    for (int hf = 0; hf < 3; ++hf)     // A row = h (rows 39..47 zeros)
      #pragma unroll
      for (int kk = 0; kk < 2; ++kk)
        af[hf][kk] = *(const f16x8*)(x0s + (hf * 16 + lr) * 64 + kk * 32 + lg * 8);
    #pragma unroll
    for (int mf = 0; mf < 2; ++mf)     // B col = m
      #pragma unroll
      for (int kk = 0; kk < 2; ++kk)
        bfr[mf][kk] = *(const f16x8*)(x2 + (wave * 32 + mf * 16 + lr) * 64 + kk * 32 + lg * 8);

    f32x4 acc[3][2];
    #pragma unroll
    for (int hf = 0; hf < 3; ++hf)
      #pragma unroll
      for (int mf = 0; mf < 2; ++mf) {
        acc[hf][mf] = __builtin_amdgcn_mfma_f32_16x16x32_f16(af[hf][0], bfr[mf][0], zero4, 0, 0, 0);
        acc[hf][mf] = __builtin_amdgcn_mfma_f32_16x16x32_f16(af[hf][1], bfr[mf][1], acc[hf][mf], 0, 0, 0);
      }

    #pragma unroll
    for (int hf = 0; hf < 3; ++hf)
      #pragma unroll
      for (int mf = 0; mf < 2; ++mf)
        #pragma unroll
        for (int r = 0; r < 4; ++r) {
          int h = hf * 16 + lg * 4 + r;
          if (h < F_N)
            Gb[(size_t)b * 4992 + h * 128 + wave * 32 + mf * 16 + lr] = (f16)acc[hf][mf][r];
        }
  }
}

// pooled3[b,o] = sum_k W3[o,k]*G[b,k] + 64*b3[o]; K=4992=156*32=4waves*39*32
// Grid 512 = 64 b-groups x 8 o-groups (16 o each). 4 waves K-split + LDS reduce.
// W3f frag-packed: slot = ks*512 + og*64 + lane.
__global__ __launch_bounds__(256) void pooled3_k(
    const f16* __restrict__ Gb,    // [1024][4992] f16
    const f16* __restrict__ W3f,   // frag-packed
    const float* __restrict__ b3,  // [128] f32
    float* __restrict__ out)       // [1024][384] f32
{
  __shared__ float red[3][64][4];  // partials from waves 1..3
  const int bg = blockIdx.x >> 3, og = blockIdx.x & 7;
  const int t = threadIdx.x;
  const int wave = t >> 6, lane = t & 63, lr = lane & 15, lg = lane >> 4;
  const f32x4 zero4 = {0.f, 0.f, 0.f, 0.f};
  const int b0 = bg * 16;

  const f16* ga = Gb + (size_t)(b0 + lr) * 4992 + lg * 8;   // A row = b
  const f16x8* wf = (const f16x8*)W3f;
  const int wbase = og * 64 + lane;
  const int ks0 = wave * 39;

  f32x4 acc = zero4;
  #pragma unroll 3
  for (int i = 0; i < 39; ++i) {
    const int ks = ks0 + i;
    f16x8 a = *(const f16x8*)(ga + ks * 32);
    f16x8 q = wf[(size_t)ks * 512 + wbase];
    acc = __builtin_amdgcn_mfma_f32_16x16x32_f16(a, q, acc, 0, 0, 0);
  }

  if (wave > 0) {
    #pragma unroll
    for (int r = 0; r < 4; ++r) red[wave - 1][lane][r] = acc[r];
  }
  __syncthreads();
  if (wave == 0) {
    #pragma unroll
    for (int w = 0; w < 3; ++w)
      #pragma unroll
      for (int r = 0; r < 4; ++r) acc[r] += red[w][lane][r];
    const int o = og * 16 + lr;
    #pragma unroll
    for (int r = 0; r < 4; ++r) {
      int bb = b0 + lg * 4 + r;
      out[(size_t)bb * 384 + 256 + o] = acc[r] + 64.0f * b3[o];
    }
  }
}

extern "C" void kernel_launch(void* const* d_in, const int* in_sizes, int n_in,
                              void* d_out, int out_size, void* d_ws, size_t ws_size,
                              hipStream_t stream) {
  const float* X0 = (const float*)d_in[0];
  const float* W1 = (const float*)d_in[1];
  const float* b1 = (const float*)d_in[2];
  const float* W2 = (const float*)d_in[3];
  const float* b2 = (const float*)d_in[4];
  const float* W3 = (const float*)d_in[5];
  const float* b3 = (const float*)d_in[6];
  float* out = (float*)d_out;

  // ws layout (f16 elements), ~13.4 MB total
  f16* W1f = (f16*)d_ws;            // 39*2*4096    = 319488
  f16* W2f = W1f + 319488;          // 39*4*4096    = 638976
  f16* W3f = W2f + 638976;          // 156*4096     = 638976
  f16* Gb  = W3f + 638976;          // 1024*4992    = 5111808

  prep_k<<<6240, 256, 0, stream>>>(W1, W2, W3, W1f, W2f, W3f);
  cin_fused_k<<<1024, 256, 0, stream>>>(X0, W1f, W2f, b1, b2, Gb, out);
  pooled3_k<<<512, 256, 0, stream>>>(Gb, W3f, b3, out);
}